// Round 1
// baseline (1594.286 us; speedup 1.0000x reference)
//
#include <hip/hip_runtime.h>

#define NS 64
#define HH 64
#define WW 64
#define VD 64
#define VH 64
#define VW 64
#define NVOX (VD*VH*VW)
#define NPIX (NS*HH*WW)
#define RES 1.5f

// ---------------- trilinear helpers ----------------

__device__ __forceinline__ float trilin_gather(const float* __restrict__ vol,
                                               float px, float py, float pz) {
    float x0 = floorf(px), y0 = floorf(py), z0 = floorf(pz);
    float fx = px - x0, fy = py - y0, fz = pz - z0;
    int ix = (int)x0, iy = (int)y0, iz = (int)z0;
    float acc = 0.f;
#pragma unroll
    for (int dz = 0; dz < 2; ++dz) {
        float wz = dz ? fz : 1.f - fz;
        int zi = iz + dz;
#pragma unroll
        for (int dy = 0; dy < 2; ++dy) {
            float wy = dy ? fy : 1.f - fy;
            int yi = iy + dy;
#pragma unroll
            for (int dx = 0; dx < 2; ++dx) {
                float wx = dx ? fx : 1.f - fx;
                int xi = ix + dx;
                bool valid = (xi >= 0) & (xi < VW) & (yi >= 0) & (yi < VH) & (zi >= 0) & (zi < VD);
                if (valid) {
                    acc = fmaf(wx * wy * wz, vol[(zi * VH + yi) * VW + xi], acc);
                }
            }
        }
    }
    return acc;
}

__device__ __forceinline__ void trilin_scatter(float* __restrict__ vol,
                                               float px, float py, float pz, float val) {
    float x0 = floorf(px), y0 = floorf(py), z0 = floorf(pz);
    float fx = px - x0, fy = py - y0, fz = pz - z0;
    int ix = (int)x0, iy = (int)y0, iz = (int)z0;
#pragma unroll
    for (int dz = 0; dz < 2; ++dz) {
        float wz = dz ? fz : 1.f - fz;
        int zi = iz + dz;
#pragma unroll
        for (int dy = 0; dy < 2; ++dy) {
            float wy = dy ? fy : 1.f - fy;
            int yi = iy + dy;
#pragma unroll
            for (int dx = 0; dx < 2; ++dx) {
                float wx = dx ? fx : 1.f - fx;
                int xi = ix + dx;
                bool valid = (xi >= 0) & (xi < VW) & (yi >= 0) & (yi < VH) & (zi >= 0) & (zi < VD);
                if (valid) {
                    atomicAdd(&vol[(zi * VH + yi) * VW + xi], wx * wy * wz * val);
                }
            }
        }
    }
}

// per-pixel base position (before PSF offset)
__device__ __forceinline__ void pixel_base(const float* __restrict__ tr, int s, int h, int w,
                                           float R[9], float* p0x, float* p0y, float* p0z) {
    const float* p = tr + s * 12;
    R[0] = p[0]; R[1] = p[1]; R[2] = p[2];  float t0 = p[3];
    R[3] = p[4]; R[4] = p[5]; R[5] = p[6];  float t1 = p[7];
    R[6] = p[8]; R[7] = p[9]; R[8] = p[10]; float t2 = p[11];
    float xs = ((float)w - 31.5f) * RES;
    float ys = ((float)h - 31.5f) * RES;
    *p0x = fmaf(R[0], xs, fmaf(R[1], ys, t0)) + 31.5f;
    *p0y = fmaf(R[3], xs, fmaf(R[4], ys, t1)) + 31.5f;
    *p0z = fmaf(R[6], xs, fmaf(R[7], ys, t2)) + 31.5f;
}

// ---------------- At (scatter) of an arbitrary slice image ----------------
__global__ __launch_bounds__(256) void k_at(const float* __restrict__ slc,
                                            float* __restrict__ vout,
                                            const float* __restrict__ tr,
                                            const float* __restrict__ psf) {
    __shared__ float s_psf[27];
    if (threadIdx.x < 27) s_psf[threadIdx.x] = psf[threadIdx.x];
    __syncthreads();
    int gid = blockIdx.x * 256 + threadIdx.x;
    int s = gid >> 12;
    int pix = gid & 4095;
    int h = pix >> 6, w = pix & 63;
    float R[9], p0x, p0y, p0z;
    pixel_base(tr, s, h, w, R, &p0x, &p0y, &p0z);
    float a = slc[gid];
#pragma unroll
    for (int k = 0; k < 27; ++k) {
        float ox = (float)(k % 3 - 1), oy = (float)((k / 3) % 3 - 1), oz = (float)(k / 9 - 1);
        float px = p0x + ox * R[0] + oy * R[1] + oz * R[2];
        float py = p0y + ox * R[3] + oy * R[4] + oz * R[5];
        float pz = p0z + ox * R[6] + oy * R[7] + oz * R[8];
        trilin_scatter(vout, px, py, pz, s_psf[k] * a);
    }
}

// ---------------- fused AtA ----------------
__global__ __launch_bounds__(256) void k_ata(const float* __restrict__ vin,
                                             float* __restrict__ vout,
                                             const float* __restrict__ tr,
                                             const float* __restrict__ psf) {
    __shared__ float s_psf[27];
    if (threadIdx.x < 27) s_psf[threadIdx.x] = psf[threadIdx.x];
    __syncthreads();
    int gid = blockIdx.x * 256 + threadIdx.x;
    int s = gid >> 12;
    int pix = gid & 4095;
    int h = pix >> 6, w = pix & 63;
    float R[9], p0x, p0y, p0z;
    pixel_base(tr, s, h, w, R, &p0x, &p0y, &p0z);
    float a = 0.f;
#pragma unroll
    for (int k = 0; k < 27; ++k) {
        float ox = (float)(k % 3 - 1), oy = (float)((k / 3) % 3 - 1), oz = (float)(k / 9 - 1);
        float px = p0x + ox * R[0] + oy * R[1] + oz * R[2];
        float py = p0y + ox * R[3] + oy * R[4] + oz * R[5];
        float pz = p0z + ox * R[6] + oy * R[7] + oz * R[8];
        a = fmaf(s_psf[k], trilin_gather(vin, px, py, pz), a);
    }
#pragma unroll
    for (int k = 0; k < 27; ++k) {
        float ox = (float)(k % 3 - 1), oy = (float)((k / 3) % 3 - 1), oz = (float)(k / 9 - 1);
        float px = p0x + ox * R[0] + oy * R[1] + oz * R[2];
        float py = p0y + ox * R[3] + oy * R[4] + oz * R[5];
        float pz = p0z + ox * R[6] + oy * R[7] + oz * R[8];
        trilin_scatter(vout, px, py, pz, s_psf[k] * a);
    }
}

// ---------------- reductions & CG updates ----------------

__device__ __forceinline__ void block_reduce_atomic(float v, float* dst) {
#pragma unroll
    for (int off = 32; off > 0; off >>= 1) v += __shfl_down(v, off, 64);
    __shared__ float s_red[4];
    int lane = threadIdx.x & 63, wid = threadIdx.x >> 6;
    if (lane == 0) s_red[wid] = v;
    __syncthreads();
    if (threadIdx.x == 0) {
        atomicAdd(dst, s_red[0] + s_red[1] + s_red[2] + s_red[3]);
    }
}

// r = b - Ap ; p = r ; scal[0] += r.r
__global__ __launch_bounds__(256) void k_residual(const float* __restrict__ b,
                                                  const float* __restrict__ Ap,
                                                  float* __restrict__ r,
                                                  float* __restrict__ p,
                                                  float* __restrict__ scal) {
    int i = blockIdx.x * 256 + threadIdx.x;
    float rv = b[i] - Ap[i];
    r[i] = rv;
    p[i] = rv;
    block_reduce_atomic(rv * rv, &scal[0]);
}

// dst += a.b
__global__ __launch_bounds__(256) void k_dot(const float* __restrict__ a,
                                             const float* __restrict__ b,
                                             float* __restrict__ dst) {
    int i = blockIdx.x * 256 + threadIdx.x;
    block_reduce_atomic(a[i] * b[i], dst);
}

// alpha = scal[0]/scal[1]; x += alpha p; r -= alpha Ap; scal[2] += r.r
__global__ __launch_bounds__(256) void k_update_xr(float* __restrict__ x,
                                                   float* __restrict__ r,
                                                   const float* __restrict__ p,
                                                   const float* __restrict__ Ap,
                                                   float* __restrict__ scal) {
    int i = blockIdx.x * 256 + threadIdx.x;
    float alpha = scal[0] / scal[1];
    x[i] = fmaf(alpha, p[i], x[i]);
    float rv = fmaf(-alpha, Ap[i], r[i]);
    r[i] = rv;
    block_reduce_atomic(rv * rv, &scal[2]);
}

// beta = scal[2]/scal[0]; p = r + beta p
__global__ __launch_bounds__(256) void k_update_p(float* __restrict__ p,
                                                  const float* __restrict__ r,
                                                  const float* __restrict__ scal) {
    int i = blockIdx.x * 256 + threadIdx.x;
    float beta = scal[2] / scal[0];
    p[i] = fmaf(beta, p[i], r[i]);
}

// alpha = scal[2]/scal[3]; out = relu(x + alpha p)
__global__ __launch_bounds__(256) void k_final(const float* __restrict__ x,
                                               const float* __restrict__ p,
                                               const float* __restrict__ scal,
                                               float* __restrict__ out) {
    int i = blockIdx.x * 256 + threadIdx.x;
    float alpha = scal[2] / scal[3];
    float v = fmaf(alpha, p[i], x[i]);
    out[i] = v > 0.f ? v : 0.f;
}

extern "C" void kernel_launch(void* const* d_in, const int* in_sizes, int n_in,
                              void* d_out, int out_size, void* d_ws, size_t ws_size,
                              hipStream_t stream) {
    const float* transforms = (const float*)d_in[0]; // 64*3*4
    const float* slices     = (const float*)d_in[1]; // 64*64*64
    const float* volume     = (const float*)d_in[2]; // 64*64*64
    const float* psf        = (const float*)d_in[3]; // 27
    float* out = (float*)d_out;

    float* vol_b  = (float*)d_ws;
    float* vol_x  = vol_b  + NVOX;
    float* vol_r  = vol_x  + NVOX;
    float* vol_p  = vol_r  + NVOX;
    float* vol_Ap = vol_p  + NVOX;
    float* scal   = vol_Ap + NVOX; // 4 floats: rr0, pAp0, rr1, pAp1

    const int nblk = NPIX / 256; // 1024
    const size_t volbytes = (size_t)NVOX * sizeof(float);

    hipMemsetAsync(scal, 0, 4 * sizeof(float), stream);

    // b = At(slices)
    hipMemsetAsync(vol_b, 0, volbytes, stream);
    k_at<<<nblk, 256, 0, stream>>>(slices, vol_b, transforms, psf);

    // x = volume
    hipMemcpyAsync(vol_x, volume, volbytes, hipMemcpyDeviceToDevice, stream);

    // Ap = AtA(x); r = b - Ap; p = r; rr0
    hipMemsetAsync(vol_Ap, 0, volbytes, stream);
    k_ata<<<nblk, 256, 0, stream>>>(vol_x, vol_Ap, transforms, psf);
    k_residual<<<nblk, 256, 0, stream>>>(vol_b, vol_Ap, vol_r, vol_p, scal);

    // iter 0
    hipMemsetAsync(vol_Ap, 0, volbytes, stream);
    k_ata<<<nblk, 256, 0, stream>>>(vol_p, vol_Ap, transforms, psf);
    k_dot<<<nblk, 256, 0, stream>>>(vol_p, vol_Ap, &scal[1]);
    k_update_xr<<<nblk, 256, 0, stream>>>(vol_x, vol_r, vol_p, vol_Ap, scal);
    k_update_p<<<nblk, 256, 0, stream>>>(vol_p, vol_r, scal);

    // iter 1
    hipMemsetAsync(vol_Ap, 0, volbytes, stream);
    k_ata<<<nblk, 256, 0, stream>>>(vol_p, vol_Ap, transforms, psf);
    k_dot<<<nblk, 256, 0, stream>>>(vol_p, vol_Ap, &scal[3]);
    k_final<<<nblk, 256, 0, stream>>>(vol_x, vol_p, scal, out);
}

// Round 2
// 688.589 us; speedup vs baseline: 2.3153x; 2.3153x over previous
//
#include <hip/hip_runtime.h>

#define NS 64
#define HH 64
#define WW 64
#define VD 64
#define VH 64
#define VW 64
#define NVOX (VD*VH*VW)
#define NPIX (NS*HH*WW)
#define RES 1.5f
#define NTAB (NS*27)

// ---------------------------------------------------------------
// Per-(slice,tap) affine table:  pos = w*U + h*V + C
// entry layout (16 floats):
//  [0..3]  a,b,c,d   : inverse of [[Ux,Vx],[Uy,Vy]]
//  [4..7]  Ux,Uy,Uz,Vx
//  [8..11] Vy,Vz,Cx,Cy
//  [12..15]Cz,psf_k,0,0
// ---------------------------------------------------------------
__global__ __launch_bounds__(256) void k_setup(const float* __restrict__ tr,
                                               const float* __restrict__ psf,
                                               float* __restrict__ tab) {
    int i = blockIdx.x * 256 + threadIdx.x;
    if (i >= NTAB) return;
    int s = i / 27, k = i % 27;
    const float* p = tr + s * 12;
    float R00 = p[0], R01 = p[1], R02 = p[2],  t0 = p[3];
    float R10 = p[4], R11 = p[5], R12 = p[6],  t1 = p[7];
    float R20 = p[8], R21 = p[9], R22 = p[10], t2 = p[11];
    float Ux = RES * R00, Uy = RES * R10, Uz = RES * R20;
    float Vx = RES * R01, Vy = RES * R11, Vz = RES * R21;
    float ox = (float)(k % 3 - 1), oy = (float)((k / 3) % 3 - 1), oz = (float)(k / 9 - 1);
    // C = t + center + R*off - 31.5*(U+V)
    float Cx = t0 + 31.5f + R00 * ox + R01 * oy + R02 * oz - 31.5f * (Ux + Vx);
    float Cy = t1 + 31.5f + R10 * ox + R11 * oy + R12 * oz - 31.5f * (Uy + Vy);
    float Cz = t2 + 31.5f + R20 * ox + R21 * oy + R22 * oz - 31.5f * (Uz + Vz);
    float inv = 1.f / (Ux * Vy - Uy * Vx);
    float* e = tab + i * 16;
    e[0] = Vy * inv;  e[1] = -Vx * inv; e[2] = -Uy * inv; e[3] = Ux * inv;
    e[4] = Ux; e[5] = Uy; e[6] = Uz; e[7] = Vx;
    e[8] = Vy; e[9] = Vz; e[10] = Cx; e[11] = Cy;
    e[12] = Cz; e[13] = psf[k]; e[14] = 0.f; e[15] = 0.f;
}

// ---------------------------------------------------------------
// Forward projection A: per pixel, 27 taps x trilinear gather
// ---------------------------------------------------------------
__device__ __forceinline__ float trilin_gather(const float* __restrict__ vol,
                                               float px, float py, float pz) {
    float x0 = floorf(px), y0 = floorf(py), z0 = floorf(pz);
    float fx = px - x0, fy = py - y0, fz = pz - z0;
    int ix = (int)x0, iy = (int)y0, iz = (int)z0;
    float acc = 0.f;
#pragma unroll
    for (int dz = 0; dz < 2; ++dz) {
        float wz = dz ? fz : 1.f - fz;
        int zi = iz + dz;
#pragma unroll
        for (int dy = 0; dy < 2; ++dy) {
            float wy = dy ? fy : 1.f - fy;
            int yi = iy + dy;
#pragma unroll
            for (int dx = 0; dx < 2; ++dx) {
                float wx = dx ? fx : 1.f - fx;
                int xi = ix + dx;
                bool valid = (xi >= 0) & (xi < VW) & (yi >= 0) & (yi < VH) & (zi >= 0) & (zi < VD);
                if (valid) acc = fmaf(wx * wy * wz, vol[(zi * VH + yi) * VW + xi], acc);
            }
        }
    }
    return acc;
}

__global__ __launch_bounds__(256) void k_a(const float* __restrict__ vin,
                                           float* __restrict__ g,
                                           const float* __restrict__ tr,
                                           const float* __restrict__ psf) {
    __shared__ float s_psf[27];
    if (threadIdx.x < 27) s_psf[threadIdx.x] = psf[threadIdx.x];
    __syncthreads();
    int gid = blockIdx.x * 256 + threadIdx.x;
    int s = gid >> 12;
    int pix = gid & 4095;
    int h = pix >> 6, w = pix & 63;
    const float* p = tr + s * 12;
    float R0 = p[0], R1 = p[1], R2 = p[2],  t0 = p[3];
    float R3 = p[4], R4 = p[5], R5 = p[6],  t1 = p[7];
    float R6 = p[8], R7 = p[9], R8 = p[10], t2 = p[11];
    float xs = ((float)w - 31.5f) * RES;
    float ys = ((float)h - 31.5f) * RES;
    float p0x = fmaf(R0, xs, fmaf(R1, ys, t0)) + 31.5f;
    float p0y = fmaf(R3, xs, fmaf(R4, ys, t1)) + 31.5f;
    float p0z = fmaf(R6, xs, fmaf(R7, ys, t2)) + 31.5f;
    float a = 0.f;
#pragma unroll
    for (int k = 0; k < 27; ++k) {
        float ox = (float)(k % 3 - 1), oy = (float)((k / 3) % 3 - 1), oz = (float)(k / 9 - 1);
        float px = p0x + ox * R0 + oy * R1 + oz * R2;
        float py = p0y + ox * R3 + oy * R4 + oz * R5;
        float pz = p0z + ox * R6 + oy * R7 + oz * R8;
        a = fmaf(s_psf[k], trilin_gather(vin, px, py, pz), a);
    }
    g[gid] = a;
}

// ---------------------------------------------------------------
// Adjoint At as a PURE GATHER over voxel columns.
// Block: 256 threads = 8 columns (tid&7) x 32 slice-groups (tid>>3, 2 slices each).
// Accumulate into per-column LDS z-arrays with LDS atomics; single write-out.
// ---------------------------------------------------------------
#define COLS_PER_BLK 8
#define COL_PAD 68

__global__ __launch_bounds__(256) void k_atg(const float* __restrict__ g,
                                             float* __restrict__ vout,
                                             const float* __restrict__ tab) {
    __shared__ float cols[COLS_PER_BLK][COL_PAD];
    for (int i = threadIdx.x; i < COLS_PER_BLK * COL_PAD; i += 256)
        (&cols[0][0])[i] = 0.f;
    __syncthreads();

    int col0 = blockIdx.x * COLS_PER_BLK;
    int lc = threadIdx.x & 7;
    int sg = threadIdx.x >> 3;        // 0..31
    int col = col0 + lc;
    int yi = col >> 6, xi = col & 63;
    float X = (float)xi, Y = (float)yi;

#pragma unroll
    for (int si = 0; si < 2; ++si) {
        int s = sg * 2 + si;
        for (int k = 0; k < 27; ++k) {
            const float* e = tab + (s * 27 + k) * 16;
            float4 e0 = *(const float4*)(e);
            float4 e1 = *(const float4*)(e + 4);
            float4 e2 = *(const float4*)(e + 8);
            float4 e3 = *(const float4*)(e + 12);
            float a = e0.x, b = e0.y, c = e0.z, d = e0.w;
            float Ux = e1.x, Uy = e1.y, Uz = e1.z, Vx = e1.w;
            float Vy = e2.x, Vz = e2.y, Cx = e2.z, Cy = e2.w;
            float Cz = e3.x, psfk = e3.y;
            float rx = X - Cx, ry = Y - Cy;
            float ws = a * rx + b * ry;
            float hs = c * rx + d * ry;
            int w0 = (int)floorf(ws), h0 = (int)floorf(hs);
#pragma unroll
            for (int dh = 0; dh < 2; ++dh) {
                int h = h0 + dh;
                if ((unsigned)h >= 64u) continue;
                float fh = (float)h;
#pragma unroll
                for (int dw = 0; dw < 2; ++dw) {
                    int w = w0 + dw;
                    if ((unsigned)w >= 64u) continue;
                    float fw = (float)w;
                    float ddx = fmaf(fw, Ux, fmaf(fh, Vx, Cx)) - X;
                    float ddy = fmaf(fw, Uy, fmaf(fh, Vy, Cy)) - Y;
                    float wx = 1.f - fabsf(ddx);
                    float wy = 1.f - fabsf(ddy);
                    if (wx <= 0.f || wy <= 0.f) continue;
                    float pz = fmaf(fw, Uz, fmaf(fh, Vz, Cz));
                    float z0f = floorf(pz);
                    float fz = pz - z0f;
                    int z0 = (int)z0f;
                    float val = wx * wy * psfk * g[(s << 12) + (h << 6) + w];
                    if ((unsigned)z0 < 64u) atomicAdd(&cols[lc][z0], val * (1.f - fz));
                    int z1 = z0 + 1;
                    if ((unsigned)z1 < 64u) atomicAdd(&cols[lc][z1], val * fz);
                }
            }
        }
    }
    __syncthreads();
    // write out: 8 cols x 64 z = 512 values
    for (int i = threadIdx.x; i < COLS_PER_BLK * 64; i += 256) {
        int lc2 = i & 7;
        int z = i >> 3;
        int col2 = col0 + lc2;
        int y2 = col2 >> 6, x2 = col2 & 63;
        vout[(z << 12) + (y2 << 6) + x2] = cols[lc2][z];
    }
}

// ---------------- reductions & CG updates ----------------

__device__ __forceinline__ void block_reduce_atomic(float v, float* dst) {
#pragma unroll
    for (int off = 32; off > 0; off >>= 1) v += __shfl_down(v, off, 64);
    __shared__ float s_red[4];
    int lane = threadIdx.x & 63, wid = threadIdx.x >> 6;
    if (lane == 0) s_red[wid] = v;
    __syncthreads();
    if (threadIdx.x == 0) atomicAdd(dst, s_red[0] + s_red[1] + s_red[2] + s_red[3]);
}

__global__ __launch_bounds__(256) void k_residual(const float* __restrict__ b,
                                                  const float* __restrict__ Ap,
                                                  float* __restrict__ r,
                                                  float* __restrict__ p,
                                                  float* __restrict__ scal) {
    int i = blockIdx.x * 256 + threadIdx.x;
    float rv = b[i] - Ap[i];
    r[i] = rv;
    p[i] = rv;
    block_reduce_atomic(rv * rv, &scal[0]);
}

__global__ __launch_bounds__(256) void k_dot(const float* __restrict__ a,
                                             const float* __restrict__ b,
                                             float* __restrict__ dst) {
    int i = blockIdx.x * 256 + threadIdx.x;
    block_reduce_atomic(a[i] * b[i], dst);
}

// alpha = scal[0]/scal[1]; x_out = x_in + alpha p; r -= alpha Ap; scal[2] += r.r
__global__ __launch_bounds__(256) void k_update_xr(const float* __restrict__ x_in,
                                                   float* __restrict__ x_out,
                                                   float* __restrict__ r,
                                                   const float* __restrict__ p,
                                                   const float* __restrict__ Ap,
                                                   float* __restrict__ scal) {
    int i = blockIdx.x * 256 + threadIdx.x;
    float alpha = scal[0] / scal[1];
    x_out[i] = fmaf(alpha, p[i], x_in[i]);
    float rv = fmaf(-alpha, Ap[i], r[i]);
    r[i] = rv;
    block_reduce_atomic(rv * rv, &scal[2]);
}

__global__ __launch_bounds__(256) void k_update_p(float* __restrict__ p,
                                                  const float* __restrict__ r,
                                                  const float* __restrict__ scal) {
    int i = blockIdx.x * 256 + threadIdx.x;
    float beta = scal[2] / scal[0];
    p[i] = fmaf(beta, p[i], r[i]);
}

__global__ __launch_bounds__(256) void k_final(const float* __restrict__ x,
                                               const float* __restrict__ p,
                                               const float* __restrict__ scal,
                                               float* __restrict__ out) {
    int i = blockIdx.x * 256 + threadIdx.x;
    float alpha = scal[2] / scal[3];
    float v = fmaf(alpha, p[i], x[i]);
    out[i] = v > 0.f ? v : 0.f;
}

extern "C" void kernel_launch(void* const* d_in, const int* in_sizes, int n_in,
                              void* d_out, int out_size, void* d_ws, size_t ws_size,
                              hipStream_t stream) {
    const float* transforms = (const float*)d_in[0];
    const float* slices     = (const float*)d_in[1];
    const float* volume     = (const float*)d_in[2];
    const float* psf        = (const float*)d_in[3];
    float* out = (float*)d_out;

    float* tab    = (float*)d_ws;            // 1728*16
    float* vol_b  = tab + NTAB * 16;
    float* vol_x  = vol_b  + NVOX;
    float* vol_r  = vol_x  + NVOX;
    float* vol_p  = vol_r  + NVOX;
    float* vol_Ap = vol_p  + NVOX;
    float* gbuf   = vol_Ap + NVOX;
    float* scal   = gbuf   + NPIX;           // 4 floats

    const int nblk = NPIX / 256;             // 1024
    const int ablk = (NVOX / 64) / COLS_PER_BLK; // 4096/8 = 512 column-blocks

    hipMemsetAsync(scal, 0, 4 * sizeof(float), stream);

    k_setup<<<(NTAB + 255) / 256, 256, 0, stream>>>(transforms, psf, tab);

    // b = At(slices)
    k_atg<<<ablk, 256, 0, stream>>>(slices, vol_b, tab);

    // Ap = AtA(x0=volume); r = b - Ap; p = r; rr0
    k_a<<<nblk, 256, 0, stream>>>(volume, gbuf, transforms, psf);
    k_atg<<<ablk, 256, 0, stream>>>(gbuf, vol_Ap, tab);
    k_residual<<<nblk, 256, 0, stream>>>(vol_b, vol_Ap, vol_r, vol_p, scal);

    // iter 0
    k_a<<<nblk, 256, 0, stream>>>(vol_p, gbuf, transforms, psf);
    k_atg<<<ablk, 256, 0, stream>>>(gbuf, vol_Ap, tab);
    k_dot<<<nblk, 256, 0, stream>>>(vol_p, vol_Ap, &scal[1]);
    k_update_xr<<<nblk, 256, 0, stream>>>(volume, vol_x, vol_r, vol_p, vol_Ap, scal);
    k_update_p<<<nblk, 256, 0, stream>>>(vol_p, vol_r, scal);

    // iter 1
    k_a<<<nblk, 256, 0, stream>>>(vol_p, gbuf, transforms, psf);
    k_atg<<<ablk, 256, 0, stream>>>(gbuf, vol_Ap, tab);
    k_dot<<<nblk, 256, 0, stream>>>(vol_p, vol_Ap, &scal[3]);
    k_final<<<nblk, 256, 0, stream>>>(vol_x, vol_p, scal, out);
}